// Round 4
// baseline (168.896 us; speedup 1.0000x reference)
//
#include <hip/hip_runtime.h>

// ---------- types ----------
typedef __attribute__((ext_vector_type(8)))  _Float16 half8;
typedef __attribute__((ext_vector_type(4)))  _Float16 half4;
typedef __attribute__((ext_vector_type(2)))  __fp16   fp16x2;
typedef __attribute__((ext_vector_type(4)))  float    f32x4;

#define MFMA16(a,b,c) __builtin_amdgcn_mfma_f32_16x16x32_f16(a,b,c,0,0,0)

// constants
#define QSCALE       0.17677669529663687f   // 32^-0.5
#define LAMBDA_INIT  0.3555090675909693f
#define OUT_SCALE    0.6444909324090307f    // 1 - LAMBDA_INIT
#define LOG2E        1.4426950408889634f
#define MSHIFT       4.0f                   // fixed softmax shift (log2 domain)

#define EXP2(x) __builtin_amdgcn_exp2f(x)   // bare v_exp_f32 (no ocml range bloat)

__device__ __forceinline__ void gld16(const void* g, void* l) {
    __builtin_amdgcn_global_load_lds(
        (const __attribute__((address_space(1))) unsigned int*)g,
        (__attribute__((address_space(3))) unsigned int*)l, 16, 0, 0);
}

// ---------- prep: fused cvt + transposes ----------
__device__ __forceinline__ void tr64(const float* __restrict__ src,
                                     _Float16* __restrict__ dst,
                                     int srcld, int dstld, int bx, int by) {
    __shared__ float t[64][65];
    int k0 = bx * 64, n0 = by * 64;
    int c = threadIdx.x & 63, rr = threadIdx.x >> 6;
#pragma unroll
    for (int ph = 0; ph < 16; ++ph) {
        int k = ph * 4 + rr;
        t[k][c] = src[(size_t)(k0 + k) * srcld + n0 + c];
    }
    __syncthreads();
#pragma unroll
    for (int ph = 0; ph < 16; ++ph) {
        int n = ph * 4 + rr;
        dst[(size_t)(n0 + n) * dstld + k0 + c] = (_Float16)t[c][n];
    }
}

__global__ __launch_bounds__(256) void k_prep(const float* __restrict__ x,
                                              const float* __restrict__ Wq,
                                              const float* __restrict__ Wkv,
                                              const float* __restrict__ Wout,
                                              _Float16* __restrict__ xh,
                                              _Float16* __restrict__ WallT,
                                              _Float16* __restrict__ WoutT) {
    int b = blockIdx.x;
    if (b < 4096) {
        int i = (b * 256 + threadIdx.x) * 4;
        f32x4 v = *(const f32x4*)(x + i);
        half4 h;
        h[0] = (_Float16)v[0]; h[1] = (_Float16)v[1];
        h[2] = (_Float16)v[2]; h[3] = (_Float16)v[3];
        *(half4*)(xh + i) = h;
    } else if (b < 4224) {
        int idx = b - 4096;                       // Wq: [1024][512] -> WallT rows 0..511
        tr64(Wq, WallT, 512, 1024, idx & 15, idx >> 4);
    } else if (b < 4480) {
        int idx = b - 4224;                       // Wkv: [1024][1024] -> WallT rows 512..1535
        tr64(Wkv, WallT + 512 * 1024, 1024, 1024, idx & 15, idx >> 4);
    } else {
        int idx = b - 4480;                       // Wout: [512][1024] -> WoutT [1024][512]
        tr64(Wout, WoutT, 1024, 512, idx & 7, idx >> 3);
    }
}

// ---------- shared GEMM main loop (double-buffered): C[128x128] = A * Bt^T ----------
// As/Bs are each 16 KB = 2 x 8 KB halves. One barrier per K-step: the barrier
// drains the prefetch issued LAST iteration (in flight across that iteration's
// MFMA phase) and guarantees prior LDS reads are done before overwrite.
__device__ __forceinline__ void gemm_loop(const _Float16* __restrict__ A,
                                          const _Float16* __restrict__ Bt,
                                          int K, int bm, int bn,
                                          char* As, char* Bs,
                                          f32x4 (&acc)[4][4]) {
    int tid = threadIdx.x, lane = tid & 63, w = tid >> 6;
    int col16 = lane & 15, quad = lane >> 4;
    int wm = (w >> 1) << 6, wn = (w & 1) << 6;
    int r0 = tid >> 2;
    int kc = (tid & 3) << 3;
    const _Float16* ga0 = A  + (size_t)(bm + r0) * K + kc;
    const _Float16* ga1 = A  + (size_t)(bm + 64 + r0) * K + kc;
    const _Float16* gb0 = Bt + (size_t)(bn + r0) * K + kc;
    const _Float16* gb1 = Bt + (size_t)(bn + 64 + r0) * K + kc;
    char* lA = As + (w << 10);
    char* lB = Bs + (w << 10);

    // prologue: stage K-step 0 into half 0
    gld16(ga0, lA);
    gld16(ga1, lA + 4096);
    gld16(gb0, lB);
    gld16(gb1, lB + 4096);

    for (int k0 = 0; k0 < K; k0 += 32) {
        __syncthreads();                   // cur half valid; prev reads complete
        int cb = (k0 >> 5) & 1;
        if (k0 + 32 < K) {                 // prefetch next K-step into other half
            int nb = (cb ^ 1) << 13;
            gld16(ga0 + k0 + 32, lA + nb);
            gld16(ga1 + k0 + 32, lA + nb + 4096);
            gld16(gb0 + k0 + 32, lB + nb);
            gld16(gb1 + k0 + 32, lB + nb + 4096);
        }
        const char* Asc = As + (cb << 13);
        const char* Bsc = Bs + (cb << 13);
        half8 af[4], bf[4];
#pragma unroll
        for (int i = 0; i < 4; ++i)
            af[i] = *(const half8*)(Asc + ((wm + i * 16 + col16) << 6) + (quad << 4));
#pragma unroll
        for (int j = 0; j < 4; ++j)
            bf[j] = *(const half8*)(Bsc + ((wn + j * 16 + col16) << 6) + (quad << 4));
#pragma unroll
        for (int i = 0; i < 4; ++i)
#pragma unroll
            for (int j = 0; j < 4; ++j)
                acc[i][j] = MFMA16(af[i], bf[j], acc[i][j]);
    }
}

// ---------- GEMM1: x @ [Wq|Wk|Wv] -> q rows + K fragments + V fragments ----------
// Kf layout: per (b*8+p, kb32): 4KB = [frag(4)][lane(64)][16B]
// Vf layout: per (b*8+p, kb32): 4KB = [t(4)][lane(64)][16B], key permutation baked in
__global__ __launch_bounds__(256) void k_gemm_qkv(const _Float16* __restrict__ xh,
                                                  const _Float16* __restrict__ WallT,
                                                  _Float16* __restrict__ qbuf,
                                                  char* __restrict__ Kf,
                                                  char* __restrict__ Vf) {
    __shared__ __align__(16) char As[16384];
    __shared__ __align__(16) char Bs[16384];
    f32x4 acc[4][4] = {};
    int bm = blockIdx.x * 128, bn = blockIdx.y * 128;
    gemm_loop(xh, WallT, 1024, bm, bn, As, Bs, acc);

    int tid = threadIdx.x, lane = tid & 63, w = tid >> 6;
    int col16 = lane & 15, quad = lane >> 4;
    int wm = (w >> 1) << 6, wn = (w & 1) << 6;

    if (bn < 512) {  // q, pre-scaled into log2-softmax domain
        const float s = QSCALE * LOG2E;
#pragma unroll
        for (int i = 0; i < 4; ++i)
#pragma unroll
            for (int j = 0; j < 4; ++j) {
                int n = bn + wn + j * 16 + col16;
                int m0 = bm + wm + i * 16 + quad * 4;
#pragma unroll
                for (int r = 0; r < 4; ++r)
                    qbuf[(size_t)(m0 + r) * 512 + n] = (_Float16)(acc[i][j][r] * s);
            }
    } else if (bn < 1024) {  // K fragments
#pragma unroll
        for (int j = 0; j < 4; ++j) {
            int n = bn + wn + j * 16 + col16 - 512;
            int pp = n >> 6, dd = n & 63, head = dd >> 5, d32 = dd & 31;
            int lbase = (d32 >> 3) << 4;
            int e2 = (d32 & 7) << 1;
            int fragb = head << 11;
#pragma unroll
            for (int i = 0; i < 4; ++i) {
                int m0 = bm + wm + i * 16 + quad * 4;
                int b = m0 >> 11, tok = m0 & 2047, kb = tok >> 5, kk = tok & 31;
                char* dst = Kf + (((size_t)((b * 8 + pp) * 64 + kb)) << 12)
                          + fragb + ((kk >> 4) << 10) + ((lbase + (kk & 15)) << 4) + e2;
#pragma unroll
                for (int r = 0; r < 4; ++r)
                    *(_Float16*)(dst + (r << 4)) = (_Float16)acc[i][j][r];
            }
        }
    } else {  // V fragments (key permutation kappa baked in)
#pragma unroll
        for (int j = 0; j < 4; ++j) {
            int n = bn + wn + j * 16 + col16 - 1024;
            int pp = n >> 6, ch = n & 63;
            int off_t = ((ch >> 4) << 10) + ((ch & 15) << 4);
#pragma unroll
            for (int i = 0; i < 4; ++i) {
                int m0 = bm + wm + i * 16 + quad * 4;
                int b = m0 >> 11, tok = m0 & 2047, kb = tok >> 5, kk = tok & 31;
                int quadv = (kk < 16) ? (kk >> 2) : ((kk - 16) >> 2);
                int e0 = (kk < 16) ? 0 : 4;
                half4 hv;
#pragma unroll
                for (int r = 0; r < 4; ++r) hv[r] = (_Float16)acc[i][j][r];
                *(half4*)(Vf + (((size_t)((b * 8 + pp) * 64 + kb)) << 12)
                          + off_t + (quadv << 8) + (e0 << 1)) = hv;
            }
        }
    }
}

// ---------- fused flash differential attention (double-buffered) ----------
// 512-thread blocks = 8 waves = 2 q-subtiles (16 rows) x 4 key-chunks (512 keys each).
// Staging: 2 x 32KB double buffer (4 chunks x [K 4KB | V 4KB] each). Prefetch of
// iter+1 issued right after the barrier, in flight across the compute phase.
// LDS 65KB -> 2 blocks/CU x 8 waves = 16 waves/CU.
// End-phase reduces the 4 chunk-partials in LDS (reusing buffer 0) and fuses the
// combine (lambda diff, RMS norm, gamma) -> writes attn f16. No Po/Pl traffic.
__global__ __launch_bounds__(512, 4) void k_attn_fused(
        const _Float16* __restrict__ qbuf,
        const char* __restrict__ Kf,
        const char* __restrict__ Vf,
        const float* __restrict__ lq1,
        const float* __restrict__ lk1,
        const float* __restrict__ lq2,
        const float* __restrict__ lk2,
        const float* __restrict__ gamma,
        _Float16* __restrict__ attnO) {
    __shared__ __align__(16) char Sh[2][32768];
    __shared__ float Ls[2][8][16];             // [map][wave][row16] l-partials

    int blk = blockIdx.x;
    int r32 = blk & 63, p = (blk >> 6) & 7, bb = blk >> 9;
    int tid = threadIdx.x, lane = tid & 63, w = tid >> 6;
    int qt2 = w & 1, c = w >> 1;               // q-subtile, key-chunk of this wave
    int col16 = lane & 15, quad = lane >> 4;

    int qrow = bb * 2048 + r32 * 32 + qt2 * 16 + col16;
    const _Float16* qb = qbuf + (size_t)qrow * 512 + p * 64;
    half8 q1 = *(const half8*)(qb + quad * 8);
    half8 q2 = *(const half8*)(qb + 32 + quad * 8);

    // staging: threads 0..255 stage K, 256..511 stage V (wave-uniform roles).
    // dest (per j-call) = buf + j*8192 + isV*4096 + (tid&255)*16.
    size_t bpoff = ((size_t)(bb * 8 + p)) << 18;              // 256KB per (b,p)
    const char* src2 = ((tid >= 256) ? Vf : Kf) + bpoff + ((tid & 255) << 4);
    int dbase = ((tid >= 256) ? 4096 : 0) + ((tid & 255) << 4);

    const f32x4 minit = {-MSHIFT, -MSHIFT, -MSHIFT, -MSHIFT};

    float l1 = 0.f, l2 = 0.f;
    f32x4 o1[4] = {}, o2[4] = {};

    // prologue: stage iter 0 into buffer 0
#pragma unroll
    for (int j = 0; j < 4; ++j)
        gld16(src2 + ((size_t)(j << 4) << 12), (char*)Sh + (j << 13) + dbase);

    for (int it = 0; it < 16; ++it) {          // 16 x 32 keys per chunk
        __syncthreads();                       // drains vmcnt -> Sh[it&1] valid; prev compute done
        if (it + 1 < 16) {                     // prefetch iter+1 into other buffer (in flight
#pragma unroll                                 //  across this iteration's compute)
            for (int j = 0; j < 4; ++j)
                gld16(src2 + ((size_t)((j << 4) + it + 1) << 12),
                      (char*)Sh + (((it + 1) & 1) << 15) + (j << 13) + dbase);
        }
        const char* kvb = (char*)Sh + ((it & 1) << 15) + (c << 13) + (lane << 4);

        half8 kf0 = *(const half8*)(kvb);
        half8 kf1 = *(const half8*)(kvb + 1024);
        half8 kf2 = *(const half8*)(kvb + 2048);
        half8 kf3 = *(const half8*)(kvb + 3072);
        f32x4 sa1 = MFMA16(kf0, q1, minit), sb1 = MFMA16(kf1, q1, minit);
        f32x4 sa2 = MFMA16(kf2, q2, minit), sb2 = MFMA16(kf3, q2, minit);

        union { half8 v; fp16x2 h[4]; } p1u, p2u;
        {
            float a0 = EXP2(sa1[0]), a1 = EXP2(sa1[1]);
            float a2 = EXP2(sa1[2]), a3 = EXP2(sa1[3]);
            float b0 = EXP2(sb1[0]), b1 = EXP2(sb1[1]);
            float b2 = EXP2(sb1[2]), b3 = EXP2(sb1[3]);
            l1 += ((a0 + a1) + (a2 + a3)) + ((b0 + b1) + (b2 + b3));
            p1u.h[0] = __builtin_amdgcn_cvt_pkrtz(a0, a1);
            p1u.h[1] = __builtin_amdgcn_cvt_pkrtz(a2, a3);
            p1u.h[2] = __builtin_amdgcn_cvt_pkrtz(b0, b1);
            p1u.h[3] = __builtin_amdgcn_cvt_pkrtz(b2, b3);
        }
        {
            float a0 = EXP2(sa2[0]), a1 = EXP2(sa2[1]);
            float a2 = EXP2(sa2[2]), a3 = EXP2(sa2[3]);
            float b0 = EXP2(sb2[0]), b1 = EXP2(sb2[1]);
            float b2 = EXP2(sb2[2]), b3 = EXP2(sb2[3]);
            l2 += ((a0 + a1) + (a2 + a3)) + ((b0 + b1) + (b2 + b3));
            p2u.h[0] = __builtin_amdgcn_cvt_pkrtz(a0, a1);
            p2u.h[1] = __builtin_amdgcn_cvt_pkrtz(a2, a3);
            p2u.h[2] = __builtin_amdgcn_cvt_pkrtz(b0, b1);
            p2u.h[3] = __builtin_amdgcn_cvt_pkrtz(b2, b3);
        }
        half8 vf0 = *(const half8*)(kvb + 4096);
        half8 vf1 = *(const half8*)(kvb + 5120);
        half8 vf2 = *(const half8*)(kvb + 6144);
        half8 vf3 = *(const half8*)(kvb + 7168);
        o1[0] = MFMA16(p1u.v, vf0, o1[0]); o2[0] = MFMA16(p2u.v, vf0, o2[0]);
        o1[1] = MFMA16(p1u.v, vf1, o1[1]); o2[1] = MFMA16(p2u.v, vf1, o2[1]);
        o1[2] = MFMA16(p1u.v, vf2, o1[2]); o2[2] = MFMA16(p2u.v, vf2, o2[2]);
        o1[3] = MFMA16(p1u.v, vf3, o1[3]); o2[3] = MFMA16(p2u.v, vf3, o2[3]);
    }

    l1 += __shfl_xor(l1, 16); l1 += __shfl_xor(l1, 32);
    l2 += __shfl_xor(l2, 16); l2 += __shfl_xor(l2, 32);

    // ---- per-wave partials -> LDS buffer 0 (safe: iter-15 compute reads buffer 1) ----
    {
        _Float16* ob = (_Float16*)((char*)Sh + ((c * 2 + qt2) << 12)) + col16;
#pragma unroll
        for (int r = 0; r < 4; ++r) {
            _Float16* od = ob + (quad * 4 + r) * 128;
#pragma unroll
            for (int t = 0; t < 4; ++t) {
                od[t * 16]      = (_Float16)o1[t][r];
                od[64 + t * 16] = (_Float16)o2[t][r];
            }
        }
        if (quad == 0) { Ls[0][w][col16] = l1; Ls[1][w][col16] = l2; }
    }
    __syncthreads();

    // ---- fused combine: 512 threads = 32 rows x 16 ch-groups of 4 ----
    int rr = tid >> 4, jj = tid & 15;
    int qrt = rr >> 4, r16 = rr & 15;
    float o1s[4] = {}, o2s[4] = {};
    float l1s = 0.f, l2s = 0.f;
#pragma unroll
    for (int cc = 0; cc < 4; ++cc) {
        const _Float16* ob = (const _Float16*)((char*)Sh + ((cc * 2 + qrt) << 12))
                           + r16 * 128 + jj * 4;
        half4 a  = *(const half4*)ob;
        half4 b2 = *(const half4*)(ob + 64);
#pragma unroll
        for (int e = 0; e < 4; ++e) { o1s[e] += (float)a[e]; o2s[e] += (float)b2[e]; }
        l1s += Ls[0][cc * 2 + qrt][r16];
        l2s += Ls[1][cc * 2 + qrt][r16];
    }
    float s1 = 0.f, s2 = 0.f;
#pragma unroll
    for (int i = 0; i < 32; ++i) { s1 += lq1[i] * lk1[i]; s2 += lq2[i] * lk2[i]; }
    float lam = __expf(s1) - __expf(s2) + LAMBDA_INIT;
    float il1 = 1.f / l1s, il2 = lam / l2s;
    float Of[4], ss = 0.f;
#pragma unroll
    for (int e = 0; e < 4; ++e) { Of[e] = o1s[e] * il1 - o2s[e] * il2; ss += Of[e] * Of[e]; }
    ss += __shfl_xor(ss, 1, 16); ss += __shfl_xor(ss, 2, 16);
    ss += __shfl_xor(ss, 4, 16); ss += __shfl_xor(ss, 8, 16);
    float rms = sqrtf(ss * 0.015625f);
    float sc = OUT_SCALE / (rms + 1e-8f);
    half4 o;
#pragma unroll
    for (int e = 0; e < 4; ++e) o[e] = (_Float16)(gamma[jj * 4 + e] * Of[e] * sc);
    *(half4*)(attnO + ((size_t)(bb * 2048 + r32 * 32 + rr) * 512) + p * 64 + jj * 4) = o;
}

// ---------- GEMM2: attn @ Wout -> fp32 out ----------
__global__ __launch_bounds__(256) void k_gemm_out(const _Float16* __restrict__ attn,
                                                  const _Float16* __restrict__ WoutT,
                                                  float* __restrict__ out) {
    __shared__ __align__(16) char As[16384];
    __shared__ __align__(16) char Bs[16384];
    f32x4 acc[4][4] = {};
    int bm = blockIdx.x * 128, bn = blockIdx.y * 128;
    gemm_loop(attn, WoutT, 512, bm, bn, As, Bs, acc);

    int tid = threadIdx.x, lane = tid & 63, w = tid >> 6;
    int col16 = lane & 15, quad = lane >> 4;
    int wm = (w >> 1) << 6, wn = (w & 1) << 6;
#pragma unroll
    for (int i = 0; i < 4; ++i)
#pragma unroll
        for (int j = 0; j < 4; ++j) {
            int n = bn + wn + j * 16 + col16;
            int m0 = bm + wm + i * 16 + quad * 4;
#pragma unroll
            for (int r = 0; r < 4; ++r)
                out[(size_t)(m0 + r) * 1024 + n] = acc[i][j][r];
        }
}

// ---------- launch ----------
extern "C" void kernel_launch(void* const* d_in, const int* in_sizes, int n_in,
                              void* d_out, int out_size, void* d_ws, size_t ws_size,
                              hipStream_t stream) {
    const float* x     = (const float*)d_in[0];
    const float* Wq    = (const float*)d_in[1];
    const float* Wkv   = (const float*)d_in[2];
    const float* Wout  = (const float*)d_in[3];
    const float* lq1   = (const float*)d_in[4];
    const float* lk1   = (const float*)d_in[5];
    const float* lq2   = (const float*)d_in[6];
    const float* lk2   = (const float*)d_in[7];
    const float* gamma = (const float*)d_in[8];
    float* out = (float*)d_out;

    char* ws = (char*)d_ws;
    // Fused attention needs no Po/Pl partial buffers: peak ws = 29.36 MB.
    _Float16* xh    = (_Float16*)(ws);                 // 4096*1024  (8 MB, dead after qkv)
    _Float16* WallT = (_Float16*)(ws + 8388608);       // 1536*1024  (3 MB, dead after qkv)
    _Float16* WoutT = (_Float16*)(ws + 11534336);      // 1024*512   (1 MB)
    _Float16* qbuf  = (_Float16*)(ws + 12582912);      // 4096*512   (4 MB)
    char*     Kf    = (char*)(ws + 16777216);          // 16*64*4096 (4 MB)
    char*     Vf    = (char*)(ws + 20971520);          // 16*64*4096 (4 MB)
    _Float16* attn  = (_Float16*)(ws + 25165824);      // 4096*512   (4 MB) -> peak 29.36 MB

    k_prep<<<4608, 256, 0, stream>>>(x, Wq, Wkv, Wout, xh, WallT, WoutT);
    k_gemm_qkv<<<dim3(32, 12), 256, 0, stream>>>(xh, WallT, qbuf, Kf, Vf);
    k_attn_fused<<<1024, 512, 0, stream>>>(qbuf, Kf, Vf, lq1, lk1, lq2, lk2, gamma, attn);
    k_gemm_out<<<dim3(32, 8), 256, 0, stream>>>(attn, WoutT, out);
}

// Round 5
// 168.324 us; speedup vs baseline: 1.0034x; 1.0034x over previous
//
#include <hip/hip_runtime.h>

// ---------- types ----------
typedef __attribute__((ext_vector_type(8)))  _Float16 half8;
typedef __attribute__((ext_vector_type(4)))  _Float16 half4;
typedef __attribute__((ext_vector_type(2)))  __fp16   fp16x2;
typedef __attribute__((ext_vector_type(4)))  float    f32x4;

#define MFMA16(a,b,c) __builtin_amdgcn_mfma_f32_16x16x32_f16(a,b,c,0,0,0)

// constants
#define QSCALE       0.17677669529663687f   // 32^-0.5
#define LAMBDA_INIT  0.3555090675909693f
#define OUT_SCALE    0.6444909324090307f    // 1 - LAMBDA_INIT
#define LOG2E        1.4426950408889634f
#define MSHIFT       4.0f                   // fixed softmax shift (log2 domain)

#define EXP2(x) __builtin_amdgcn_exp2f(x)   // bare v_exp_f32 (no ocml range bloat)

__device__ __forceinline__ void gld16(const void* g, void* l) {
    __builtin_amdgcn_global_load_lds(
        (const __attribute__((address_space(1))) unsigned int*)g,
        (__attribute__((address_space(3))) unsigned int*)l, 16, 0, 0);
}

// ---------- prep: fused cvt + transposes ----------
__device__ __forceinline__ void tr64(const float* __restrict__ src,
                                     _Float16* __restrict__ dst,
                                     int srcld, int dstld, int bx, int by) {
    __shared__ float t[64][65];
    int k0 = bx * 64, n0 = by * 64;
    int c = threadIdx.x & 63, rr = threadIdx.x >> 6;
#pragma unroll
    for (int ph = 0; ph < 16; ++ph) {
        int k = ph * 4 + rr;
        t[k][c] = src[(size_t)(k0 + k) * srcld + n0 + c];
    }
    __syncthreads();
#pragma unroll
    for (int ph = 0; ph < 16; ++ph) {
        int n = ph * 4 + rr;
        dst[(size_t)(n0 + n) * dstld + k0 + c] = (_Float16)t[c][n];
    }
}

__global__ __launch_bounds__(256) void k_prep(const float* __restrict__ x,
                                              const float* __restrict__ Wq,
                                              const float* __restrict__ Wkv,
                                              const float* __restrict__ Wout,
                                              _Float16* __restrict__ xh,
                                              _Float16* __restrict__ WallT,
                                              _Float16* __restrict__ WoutT) {
    int b = blockIdx.x;
    if (b < 4096) {
        int i = (b * 256 + threadIdx.x) * 4;
        f32x4 v = *(const f32x4*)(x + i);
        half4 h;
        h[0] = (_Float16)v[0]; h[1] = (_Float16)v[1];
        h[2] = (_Float16)v[2]; h[3] = (_Float16)v[3];
        *(half4*)(xh + i) = h;
    } else if (b < 4224) {
        int idx = b - 4096;                       // Wq: [1024][512] -> WallT rows 0..511
        tr64(Wq, WallT, 512, 1024, idx & 15, idx >> 4);
    } else if (b < 4480) {
        int idx = b - 4224;                       // Wkv: [1024][1024] -> WallT rows 512..1535
        tr64(Wkv, WallT + 512 * 1024, 1024, 1024, idx & 15, idx >> 4);
    } else {
        int idx = b - 4480;                       // Wout: [512][1024] -> WoutT [1024][512]
        tr64(Wout, WoutT, 1024, 512, idx & 7, idx >> 3);
    }
}

// ---------- shared GEMM main loop (double-buffered): C[128x128] = A * Bt^T ----------
__device__ __forceinline__ void gemm_loop(const _Float16* __restrict__ A,
                                          const _Float16* __restrict__ Bt,
                                          int K, int bm, int bn,
                                          char* As, char* Bs,
                                          f32x4 (&acc)[4][4]) {
    int tid = threadIdx.x, lane = tid & 63, w = tid >> 6;
    int col16 = lane & 15, quad = lane >> 4;
    int wm = (w >> 1) << 6, wn = (w & 1) << 6;
    int r0 = tid >> 2;
    int kc = (tid & 3) << 3;
    const _Float16* ga0 = A  + (size_t)(bm + r0) * K + kc;
    const _Float16* ga1 = A  + (size_t)(bm + 64 + r0) * K + kc;
    const _Float16* gb0 = Bt + (size_t)(bn + r0) * K + kc;
    const _Float16* gb1 = Bt + (size_t)(bn + 64 + r0) * K + kc;
    char* lA = As + (w << 10);
    char* lB = Bs + (w << 10);

    // prologue: stage K-step 0 into half 0
    gld16(ga0, lA);
    gld16(ga1, lA + 4096);
    gld16(gb0, lB);
    gld16(gb1, lB + 4096);

    for (int k0 = 0; k0 < K; k0 += 32) {
        __syncthreads();                   // cur half valid; prev reads complete
        int cb = (k0 >> 5) & 1;
        if (k0 + 32 < K) {                 // prefetch next K-step into other half
            int nb = (cb ^ 1) << 13;
            gld16(ga0 + k0 + 32, lA + nb);
            gld16(ga1 + k0 + 32, lA + nb + 4096);
            gld16(gb0 + k0 + 32, lB + nb);
            gld16(gb1 + k0 + 32, lB + nb + 4096);
        }
        const char* Asc = As + (cb << 13);
        const char* Bsc = Bs + (cb << 13);
        half8 af[4], bf[4];
#pragma unroll
        for (int i = 0; i < 4; ++i)
            af[i] = *(const half8*)(Asc + ((wm + i * 16 + col16) << 6) + (quad << 4));
#pragma unroll
        for (int j = 0; j < 4; ++j)
            bf[j] = *(const half8*)(Bsc + ((wn + j * 16 + col16) << 6) + (quad << 4));
#pragma unroll
        for (int i = 0; i < 4; ++i)
#pragma unroll
            for (int j = 0; j < 4; ++j)
                acc[i][j] = MFMA16(af[i], bf[j], acc[i][j]);
    }
}

// ---------- GEMM1: x @ [Wq|Wk|Wv] -> q rows + K fragments + V fragments ----------
// Kf layout: per (b*8+p, kb32): 4KB = [frag(4)][lane(64)][16B]
// Vf layout: per (b*8+p, kb32): 4KB = [t(4)][lane(64)][16B], key permutation baked in
__global__ __launch_bounds__(256) void k_gemm_qkv(const _Float16* __restrict__ xh,
                                                  const _Float16* __restrict__ WallT,
                                                  _Float16* __restrict__ qbuf,
                                                  char* __restrict__ Kf,
                                                  char* __restrict__ Vf) {
    __shared__ __align__(16) char As[16384];
    __shared__ __align__(16) char Bs[16384];
    f32x4 acc[4][4] = {};
    int bm = blockIdx.x * 128, bn = blockIdx.y * 128;
    gemm_loop(xh, WallT, 1024, bm, bn, As, Bs, acc);

    int tid = threadIdx.x, lane = tid & 63, w = tid >> 6;
    int col16 = lane & 15, quad = lane >> 4;
    int wm = (w >> 1) << 6, wn = (w & 1) << 6;

    if (bn < 512) {  // q, pre-scaled into log2-softmax domain
        const float s = QSCALE * LOG2E;
#pragma unroll
        for (int i = 0; i < 4; ++i)
#pragma unroll
            for (int j = 0; j < 4; ++j) {
                int n = bn + wn + j * 16 + col16;
                int m0 = bm + wm + i * 16 + quad * 4;
#pragma unroll
                for (int r = 0; r < 4; ++r)
                    qbuf[(size_t)(m0 + r) * 512 + n] = (_Float16)(acc[i][j][r] * s);
            }
    } else if (bn < 1024) {  // K fragments
#pragma unroll
        for (int j = 0; j < 4; ++j) {
            int n = bn + wn + j * 16 + col16 - 512;
            int pp = n >> 6, dd = n & 63, head = dd >> 5, d32 = dd & 31;
            int lbase = (d32 >> 3) << 4;
            int e2 = (d32 & 7) << 1;
            int fragb = head << 11;
#pragma unroll
            for (int i = 0; i < 4; ++i) {
                int m0 = bm + wm + i * 16 + quad * 4;
                int b = m0 >> 11, tok = m0 & 2047, kb = tok >> 5, kk = tok & 31;
                char* dst = Kf + (((size_t)((b * 8 + pp) * 64 + kb)) << 12)
                          + fragb + ((kk >> 4) << 10) + ((lbase + (kk & 15)) << 4) + e2;
#pragma unroll
                for (int r = 0; r < 4; ++r)
                    *(_Float16*)(dst + (r << 4)) = (_Float16)acc[i][j][r];
            }
        }
    } else {  // V fragments (key permutation kappa baked in)
#pragma unroll
        for (int j = 0; j < 4; ++j) {
            int n = bn + wn + j * 16 + col16 - 1024;
            int pp = n >> 6, ch = n & 63;
            int off_t = ((ch >> 4) << 10) + ((ch & 15) << 4);
#pragma unroll
            for (int i = 0; i < 4; ++i) {
                int m0 = bm + wm + i * 16 + quad * 4;
                int b = m0 >> 11, tok = m0 & 2047, kb = tok >> 5, kk = tok & 31;
                int quadv = (kk < 16) ? (kk >> 2) : ((kk - 16) >> 2);
                int e0 = (kk < 16) ? 0 : 4;
                half4 hv;
#pragma unroll
                for (int r = 0; r < 4; ++r) hv[r] = (_Float16)acc[i][j][r];
                *(half4*)(Vf + (((size_t)((b * 8 + pp) * 64 + kb)) << 12)
                          + off_t + (quadv << 8) + (e0 << 1)) = hv;
            }
        }
    }
}

// ---------- fused flash differential attention ----------
// 512-thread blocks = 8 waves = 2 q-subtiles (16 rows) x 4 key-chunks (512 keys each).
// K: LDS double-buffer 2 x 16KB (gld16, all 512 threads stage, 2 calls each).
// V: read DIRECTLY from global into VGPRs (per-lane 16B MFMA B-fragments; L2-resident;
//    latency hidden under QK-MFMA + exp). LDS 33.8KB -> 4 blocks/CU = 32 waves/CU.
// V loads issued BEFORE the K prefetch so in-order vmcnt retirement doesn't chain
// the V waits behind the LDS prefetch.
// End-phase reduces the 4 chunk-partials in LDS (overlaying both K buffers; barrier
// added) and fuses the combine (lambda diff, RMS norm, gamma) -> writes attn f16.
__global__ __launch_bounds__(512, 4) void k_attn_fused(
        const _Float16* __restrict__ qbuf,
        const char* __restrict__ Kf,
        const char* __restrict__ Vf,
        const float* __restrict__ lq1,
        const float* __restrict__ lk1,
        const float* __restrict__ lq2,
        const float* __restrict__ lk2,
        const float* __restrict__ gamma,
        _Float16* __restrict__ attnO) {
    __shared__ __align__(16) char Sh[2][16384];   // K-only double buffer
    __shared__ float Ls[2][8][16];                // [map][wave][row16] l-partials

    int blk = blockIdx.x;
    int r32 = blk & 63, p = (blk >> 6) & 7, bb = blk >> 9;
    int tid = threadIdx.x, lane = tid & 63, w = tid >> 6;
    int qt2 = w & 1, c = w >> 1;               // q-subtile, key-chunk of this wave
    int col16 = lane & 15, quad = lane >> 4;

    int qrow = bb * 2048 + r32 * 32 + qt2 * 16 + col16;
    const _Float16* qb = qbuf + (size_t)qrow * 512 + p * 64;
    half8 q1 = *(const half8*)(qb + quad * 8);
    half8 q2 = *(const half8*)(qb + 32 + quad * 8);

    // K staging: thread t handles chunks j0=(t>>8)*2 and j0+1, one 16B slot each.
    // LDS dest is linear per chunk: buf + j*4096 + (t&255)*16 (wave-uniform + lane*16).
    size_t bpoff = ((size_t)(bb * 8 + p)) << 18;              // 256KB per (b,p)
    int j0 = (tid >> 8) << 1;
    const char* ks = Kf + bpoff + ((size_t)j0 << 16) + ((tid & 255) << 4);
    int dko = (j0 << 12) + ((tid & 255) << 4);

    // V direct-from-global: per-wave chunk c, key-block kb = c*16 + it.
    const char* vsrc = Vf + bpoff + ((size_t)c << 16) + (lane << 4);

    const f32x4 minit = {-MSHIFT, -MSHIFT, -MSHIFT, -MSHIFT};

    float l1 = 0.f, l2 = 0.f;
    f32x4 o1[4] = {}, o2[4] = {};

    // prologue: stage K iter 0 into buffer 0
    gld16(ks, (char*)Sh + dko);
    gld16(ks + 65536, (char*)Sh + dko + 4096);

    for (int it = 0; it < 16; ++it) {          // 16 x 32 keys per chunk
        __syncthreads();                       // drains vmcnt -> K[it] valid; prev reads done

        // V fragments for THIS iteration: global -> VGPR (issued first; consumed by PV)
        half8 vf0 = *(const half8*)(vsrc);
        half8 vf1 = *(const half8*)(vsrc + 1024);
        half8 vf2 = *(const half8*)(vsrc + 2048);
        half8 vf3 = *(const half8*)(vsrc + 3072);
        vsrc += 4096;

        if (it + 1 < 16) {                     // prefetch K[it+1] into other buffer
            char* d = (char*)Sh + (((it + 1) & 1) << 14) + dko;
            gld16(ks + ((size_t)(it + 1) << 12), d);
            gld16(ks + 65536 + ((size_t)(it + 1) << 12), d + 4096);
        }
        const char* kvb = (char*)Sh + ((it & 1) << 14) + (c << 12) + (lane << 4);

        half8 kf0 = *(const half8*)(kvb);
        half8 kf1 = *(const half8*)(kvb + 1024);
        half8 kf2 = *(const half8*)(kvb + 2048);
        half8 kf3 = *(const half8*)(kvb + 3072);
        f32x4 sa1 = MFMA16(kf0, q1, minit), sb1 = MFMA16(kf1, q1, minit);
        f32x4 sa2 = MFMA16(kf2, q2, minit), sb2 = MFMA16(kf3, q2, minit);

        union { half8 v; fp16x2 h[4]; } p1u, p2u;
        {
            float a0 = EXP2(sa1[0]), a1 = EXP2(sa1[1]);
            float a2 = EXP2(sa1[2]), a3 = EXP2(sa1[3]);
            float b0 = EXP2(sb1[0]), b1 = EXP2(sb1[1]);
            float b2 = EXP2(sb1[2]), b3 = EXP2(sb1[3]);
            l1 += ((a0 + a1) + (a2 + a3)) + ((b0 + b1) + (b2 + b3));
            p1u.h[0] = __builtin_amdgcn_cvt_pkrtz(a0, a1);
            p1u.h[1] = __builtin_amdgcn_cvt_pkrtz(a2, a3);
            p1u.h[2] = __builtin_amdgcn_cvt_pkrtz(b0, b1);
            p1u.h[3] = __builtin_amdgcn_cvt_pkrtz(b2, b3);
        }
        {
            float a0 = EXP2(sa2[0]), a1 = EXP2(sa2[1]);
            float a2 = EXP2(sa2[2]), a3 = EXP2(sa2[3]);
            float b0 = EXP2(sb2[0]), b1 = EXP2(sb2[1]);
            float b2 = EXP2(sb2[2]), b3 = EXP2(sb2[3]);
            l2 += ((a0 + a1) + (a2 + a3)) + ((b0 + b1) + (b2 + b3));
            p2u.h[0] = __builtin_amdgcn_cvt_pkrtz(a0, a1);
            p2u.h[1] = __builtin_amdgcn_cvt_pkrtz(a2, a3);
            p2u.h[2] = __builtin_amdgcn_cvt_pkrtz(b0, b1);
            p2u.h[3] = __builtin_amdgcn_cvt_pkrtz(b2, b3);
        }
        o1[0] = MFMA16(p1u.v, vf0, o1[0]); o2[0] = MFMA16(p2u.v, vf0, o2[0]);
        o1[1] = MFMA16(p1u.v, vf1, o1[1]); o2[1] = MFMA16(p2u.v, vf1, o2[1]);
        o1[2] = MFMA16(p1u.v, vf2, o1[2]); o2[2] = MFMA16(p2u.v, vf2, o2[2]);
        o1[3] = MFMA16(p1u.v, vf3, o1[3]); o2[3] = MFMA16(p2u.v, vf3, o2[3]);
    }

    l1 += __shfl_xor(l1, 16); l1 += __shfl_xor(l1, 32);
    l2 += __shfl_xor(l2, 16); l2 += __shfl_xor(l2, 32);

    // ---- per-wave partials -> LDS (overlays BOTH K buffers; must sync first) ----
    __syncthreads();                           // all iter-15 K reads complete
    {
        _Float16* ob = (_Float16*)((char*)Sh + ((c * 2 + qt2) << 12)) + col16;
#pragma unroll
        for (int r = 0; r < 4; ++r) {
            _Float16* od = ob + (quad * 4 + r) * 128;
#pragma unroll
            for (int t = 0; t < 4; ++t) {
                od[t * 16]      = (_Float16)o1[t][r];
                od[64 + t * 16] = (_Float16)o2[t][r];
            }
        }
        if (quad == 0) { Ls[0][w][col16] = l1; Ls[1][w][col16] = l2; }
    }
    __syncthreads();

    // ---- fused combine: 512 threads = 32 rows x 16 ch-groups of 4 ----
    int rr = tid >> 4, jj = tid & 15;
    int qrt = rr >> 4, r16 = rr & 15;
    float o1s[4] = {}, o2s[4] = {};
    float l1s = 0.f, l2s = 0.f;
#pragma unroll
    for (int cc = 0; cc < 4; ++cc) {
        const _Float16* ob = (const _Float16*)((char*)Sh + ((cc * 2 + qrt) << 12))
                           + r16 * 128 + jj * 4;
        half4 a  = *(const half4*)ob;
        half4 b2 = *(const half4*)(ob + 64);
#pragma unroll
        for (int e = 0; e < 4; ++e) { o1s[e] += (float)a[e]; o2s[e] += (float)b2[e]; }
        l1s += Ls[0][cc * 2 + qrt][r16];
        l2s += Ls[1][cc * 2 + qrt][r16];
    }
    float s1 = 0.f, s2 = 0.f;
#pragma unroll
    for (int i = 0; i < 32; ++i) { s1 += lq1[i] * lk1[i]; s2 += lq2[i] * lk2[i]; }
    float lam = __expf(s1) - __expf(s2) + LAMBDA_INIT;
    float il1 = 1.f / l1s, il2 = lam / l2s;
    float Of[4], ss = 0.f;
#pragma unroll
    for (int e = 0; e < 4; ++e) { Of[e] = o1s[e] * il1 - o2s[e] * il2; ss += Of[e] * Of[e]; }
    ss += __shfl_xor(ss, 1, 16); ss += __shfl_xor(ss, 2, 16);
    ss += __shfl_xor(ss, 4, 16); ss += __shfl_xor(ss, 8, 16);
    float rms = sqrtf(ss * 0.015625f);
    float sc = OUT_SCALE / (rms + 1e-8f);
    half4 o;
#pragma unroll
    for (int e = 0; e < 4; ++e) o[e] = (_Float16)(gamma[jj * 4 + e] * Of[e] * sc);
    *(half4*)(attnO + ((size_t)(bb * 2048 + r32 * 32 + rr) * 512) + p * 64 + jj * 4) = o;
}

// ---------- GEMM2: attn @ Wout -> fp32 out ----------
__global__ __launch_bounds__(256) void k_gemm_out(const _Float16* __restrict__ attn,
                                                  const _Float16* __restrict__ WoutT,
                                                  float* __restrict__ out) {
    __shared__ __align__(16) char As[16384];
    __shared__ __align__(16) char Bs[16384];
    f32x4 acc[4][4] = {};
    int bm = blockIdx.x * 128, bn = blockIdx.y * 128;
    gemm_loop(attn, WoutT, 512, bm, bn, As, Bs, acc);

    int tid = threadIdx.x, lane = tid & 63, w = tid >> 6;
    int col16 = lane & 15, quad = lane >> 4;
    int wm = (w >> 1) << 6, wn = (w & 1) << 6;
#pragma unroll
    for (int i = 0; i < 4; ++i)
#pragma unroll
        for (int j = 0; j < 4; ++j) {
            int n = bn + wn + j * 16 + col16;
            int m0 = bm + wm + i * 16 + quad * 4;
#pragma unroll
            for (int r = 0; r < 4; ++r)
                out[(size_t)(m0 + r) * 1024 + n] = acc[i][j][r];
        }
}

// ---------- launch ----------
extern "C" void kernel_launch(void* const* d_in, const int* in_sizes, int n_in,
                              void* d_out, int out_size, void* d_ws, size_t ws_size,
                              hipStream_t stream) {
    const float* x     = (const float*)d_in[0];
    const float* Wq    = (const float*)d_in[1];
    const float* Wkv   = (const float*)d_in[2];
    const float* Wout  = (const float*)d_in[3];
    const float* lq1   = (const float*)d_in[4];
    const float* lk1   = (const float*)d_in[5];
    const float* lq2   = (const float*)d_in[6];
    const float* lk2   = (const float*)d_in[7];
    const float* gamma = (const float*)d_in[8];
    float* out = (float*)d_out;

    char* ws = (char*)d_ws;
    // Fused attention needs no Po/Pl partial buffers: peak ws = 29.36 MB.
    _Float16* xh    = (_Float16*)(ws);                 // 4096*1024  (8 MB, dead after qkv)
    _Float16* WallT = (_Float16*)(ws + 8388608);       // 1536*1024  (3 MB, dead after qkv)
    _Float16* WoutT = (_Float16*)(ws + 11534336);      // 1024*512   (1 MB)
    _Float16* qbuf  = (_Float16*)(ws + 12582912);      // 4096*512   (4 MB)
    char*     Kf    = (char*)(ws + 16777216);          // 16*64*4096 (4 MB)
    char*     Vf    = (char*)(ws + 20971520);          // 16*64*4096 (4 MB)
    _Float16* attn  = (_Float16*)(ws + 25165824);      // 4096*512   (4 MB) -> peak 29.36 MB

    k_prep<<<4608, 256, 0, stream>>>(x, Wq, Wkv, Wout, xh, WallT, WoutT);
    k_gemm_qkv<<<dim3(32, 12), 256, 0, stream>>>(xh, WallT, qbuf, Kf, Vf);
    k_attn_fused<<<1024, 512, 0, stream>>>(qbuf, Kf, Vf, lq1, lk1, lq2, lk2, gamma, attn);
    k_gemm_out<<<dim3(32, 8), 256, 0, stream>>>(attn, WoutT, out);
}

// Round 6
// 164.848 us; speedup vs baseline: 1.0246x; 1.0211x over previous
//
#include <hip/hip_runtime.h>

// ---------- types ----------
typedef __attribute__((ext_vector_type(8)))  _Float16 half8;
typedef __attribute__((ext_vector_type(4)))  _Float16 half4;
typedef __attribute__((ext_vector_type(2)))  __fp16   fp16x2;
typedef __attribute__((ext_vector_type(4)))  float    f32x4;

#define MFMA16(a,b,c) __builtin_amdgcn_mfma_f32_16x16x32_f16(a,b,c,0,0,0)

// constants
#define QSCALE       0.17677669529663687f   // 32^-0.5
#define LAMBDA_INIT  0.3555090675909693f
#define OUT_SCALE    0.6444909324090307f    // 1 - LAMBDA_INIT
#define LOG2E        1.4426950408889634f
#define MSHIFT       4.0f                   // fixed softmax shift (log2 domain)

#define EXP2(x) __builtin_amdgcn_exp2f(x)   // bare v_exp_f32 (no ocml range bloat)

__device__ __forceinline__ void gld16(const void* g, void* l) {
    __builtin_amdgcn_global_load_lds(
        (const __attribute__((address_space(1))) unsigned int*)g,
        (__attribute__((address_space(3))) unsigned int*)l, 16, 0, 0);
}

// ---------- prep: fused cvt + transposes ----------
__device__ __forceinline__ void tr64(const float* __restrict__ src,
                                     _Float16* __restrict__ dst,
                                     int srcld, int dstld, int bx, int by) {
    __shared__ float t[64][65];
    int k0 = bx * 64, n0 = by * 64;
    int c = threadIdx.x & 63, rr = threadIdx.x >> 6;
#pragma unroll
    for (int ph = 0; ph < 16; ++ph) {
        int k = ph * 4 + rr;
        t[k][c] = src[(size_t)(k0 + k) * srcld + n0 + c];
    }
    __syncthreads();
#pragma unroll
    for (int ph = 0; ph < 16; ++ph) {
        int n = ph * 4 + rr;
        dst[(size_t)(n0 + n) * dstld + k0 + c] = (_Float16)t[c][n];
    }
}

__global__ __launch_bounds__(256) void k_prep(const float* __restrict__ x,
                                              const float* __restrict__ Wq,
                                              const float* __restrict__ Wkv,
                                              const float* __restrict__ Wout,
                                              _Float16* __restrict__ xh,
                                              _Float16* __restrict__ WallT,
                                              _Float16* __restrict__ WoutT) {
    int b = blockIdx.x;
    if (b < 4096) {
        int i = (b * 256 + threadIdx.x) * 4;
        f32x4 v = *(const f32x4*)(x + i);
        half4 h;
        h[0] = (_Float16)v[0]; h[1] = (_Float16)v[1];
        h[2] = (_Float16)v[2]; h[3] = (_Float16)v[3];
        *(half4*)(xh + i) = h;
    } else if (b < 4224) {
        int idx = b - 4096;                       // Wq: [1024][512] -> WallT rows 0..511
        tr64(Wq, WallT, 512, 1024, idx & 15, idx >> 4);
    } else if (b < 4480) {
        int idx = b - 4224;                       // Wkv: [1024][1024] -> WallT rows 512..1535
        tr64(Wkv, WallT + 512 * 1024, 1024, 1024, idx & 15, idx >> 4);
    } else {
        int idx = b - 4480;                       // Wout: [512][1024] -> WoutT [1024][512]
        tr64(Wout, WoutT, 1024, 512, idx & 7, idx >> 3);
    }
}

// ---------- shared GEMM main loop (double-buffered): C[128x128] = A * Bt^T ----------
__device__ __forceinline__ void gemm_loop(const _Float16* __restrict__ A,
                                          const _Float16* __restrict__ Bt,
                                          int K, int bm, int bn,
                                          char* As, char* Bs,
                                          f32x4 (&acc)[4][4]) {
    int tid = threadIdx.x, lane = tid & 63, w = tid >> 6;
    int col16 = lane & 15, quad = lane >> 4;
    int wm = (w >> 1) << 6, wn = (w & 1) << 6;
    int r0 = tid >> 2;
    int kc = (tid & 3) << 3;
    const _Float16* ga0 = A  + (size_t)(bm + r0) * K + kc;
    const _Float16* ga1 = A  + (size_t)(bm + 64 + r0) * K + kc;
    const _Float16* gb0 = Bt + (size_t)(bn + r0) * K + kc;
    const _Float16* gb1 = Bt + (size_t)(bn + 64 + r0) * K + kc;
    char* lA = As + (w << 10);
    char* lB = Bs + (w << 10);

    // prologue: stage K-step 0 into half 0
    gld16(ga0, lA);
    gld16(ga1, lA + 4096);
    gld16(gb0, lB);
    gld16(gb1, lB + 4096);

    for (int k0 = 0; k0 < K; k0 += 32) {
        __syncthreads();                   // cur half valid; prev reads complete
        int cb = (k0 >> 5) & 1;
        if (k0 + 32 < K) {                 // prefetch next K-step into other half
            int nb = (cb ^ 1) << 13;
            gld16(ga0 + k0 + 32, lA + nb);
            gld16(ga1 + k0 + 32, lA + nb + 4096);
            gld16(gb0 + k0 + 32, lB + nb);
            gld16(gb1 + k0 + 32, lB + nb + 4096);
        }
        const char* Asc = As + (cb << 13);
        const char* Bsc = Bs + (cb << 13);
        half8 af[4], bf[4];
#pragma unroll
        for (int i = 0; i < 4; ++i)
            af[i] = *(const half8*)(Asc + ((wm + i * 16 + col16) << 6) + (quad << 4));
#pragma unroll
        for (int j = 0; j < 4; ++j)
            bf[j] = *(const half8*)(Bsc + ((wn + j * 16 + col16) << 6) + (quad << 4));
#pragma unroll
        for (int i = 0; i < 4; ++i)
#pragma unroll
            for (int j = 0; j < 4; ++j)
                acc[i][j] = MFMA16(af[i], bf[j], acc[i][j]);
    }
}

// ---------- GEMM1: x @ [Wq|Wk|Wv] -> q rows + K fragments + V fragments ----------
// Kf layout: per (b*8+p, kb32): 4KB = [frag(4)][lane(64)][16B]
// Vf layout: per (b*8+p, kb32): 4KB = [t(4)][lane(64)][16B], key permutation baked in
__global__ __launch_bounds__(256) void k_gemm_qkv(const _Float16* __restrict__ xh,
                                                  const _Float16* __restrict__ WallT,
                                                  _Float16* __restrict__ qbuf,
                                                  char* __restrict__ Kf,
                                                  char* __restrict__ Vf) {
    __shared__ __align__(16) char As[16384];
    __shared__ __align__(16) char Bs[16384];
    f32x4 acc[4][4] = {};
    int bm = blockIdx.x * 128, bn = blockIdx.y * 128;
    gemm_loop(xh, WallT, 1024, bm, bn, As, Bs, acc);

    int tid = threadIdx.x, lane = tid & 63, w = tid >> 6;
    int col16 = lane & 15, quad = lane >> 4;
    int wm = (w >> 1) << 6, wn = (w & 1) << 6;

    if (bn < 512) {  // q, pre-scaled into log2-softmax domain
        const float s = QSCALE * LOG2E;
#pragma unroll
        for (int i = 0; i < 4; ++i)
#pragma unroll
            for (int j = 0; j < 4; ++j) {
                int n = bn + wn + j * 16 + col16;
                int m0 = bm + wm + i * 16 + quad * 4;
#pragma unroll
                for (int r = 0; r < 4; ++r)
                    qbuf[(size_t)(m0 + r) * 512 + n] = (_Float16)(acc[i][j][r] * s);
            }
    } else if (bn < 1024) {  // K fragments
#pragma unroll
        for (int j = 0; j < 4; ++j) {
            int n = bn + wn + j * 16 + col16 - 512;
            int pp = n >> 6, dd = n & 63, head = dd >> 5, d32 = dd & 31;
            int lbase = (d32 >> 3) << 4;
            int e2 = (d32 & 7) << 1;
            int fragb = head << 11;
#pragma unroll
            for (int i = 0; i < 4; ++i) {
                int m0 = bm + wm + i * 16 + quad * 4;
                int b = m0 >> 11, tok = m0 & 2047, kb = tok >> 5, kk = tok & 31;
                char* dst = Kf + (((size_t)((b * 8 + pp) * 64 + kb)) << 12)
                          + fragb + ((kk >> 4) << 10) + ((lbase + (kk & 15)) << 4) + e2;
#pragma unroll
                for (int r = 0; r < 4; ++r)
                    *(_Float16*)(dst + (r << 4)) = (_Float16)acc[i][j][r];
            }
        }
    } else {  // V fragments (key permutation kappa baked in)
#pragma unroll
        for (int j = 0; j < 4; ++j) {
            int n = bn + wn + j * 16 + col16 - 1024;
            int pp = n >> 6, ch = n & 63;
            int off_t = ((ch >> 4) << 10) + ((ch & 15) << 4);
#pragma unroll
            for (int i = 0; i < 4; ++i) {
                int m0 = bm + wm + i * 16 + quad * 4;
                int b = m0 >> 11, tok = m0 & 2047, kb = tok >> 5, kk = tok & 31;
                int quadv = (kk < 16) ? (kk >> 2) : ((kk - 16) >> 2);
                int e0 = (kk < 16) ? 0 : 4;
                half4 hv;
#pragma unroll
                for (int r = 0; r < 4; ++r) hv[r] = (_Float16)acc[i][j][r];
                *(half4*)(Vf + (((size_t)((b * 8 + pp) * 64 + kb)) << 12)
                          + off_t + (quadv << 8) + (e0 << 1)) = hv;
            }
        }
    }
}

// ---------- fused flash differential attention ----------
// 512-thread blocks = 8 waves = 2 q-subtiles (16 rows) x 4 key-chunks (512 keys each).
// K: LDS double-buffer 2 x 16KB. V: direct global->VGPR. LDS 33.8KB.
// XCD-LOCALITY SWIZZLE: grid = 16 (b,p)-groups x 64 q-tiles; each group's K/V
// working set is 512KB. Default round-robin block->XCD puts all 16 groups (8MB)
// on every XCD's 4MB L2 -> thrash -> L3-BW bound (~16.5 TB/s demand). Remap so
// xcd = blk&7 hosts only groups {2*xcd, 2*xcd+1} (1MB, L2-fits): all re-reads
// become local-L2 hits. If HW maps blocks chunked instead of rr, this degenerates
// to the old distribution (no downside).
// End-phase reduces the 4 chunk-partials in LDS and fuses the combine.
__global__ __launch_bounds__(512, 4) void k_attn_fused(
        const _Float16* __restrict__ qbuf,
        const char* __restrict__ Kf,
        const char* __restrict__ Vf,
        const float* __restrict__ lq1,
        const float* __restrict__ lk1,
        const float* __restrict__ lq2,
        const float* __restrict__ lk2,
        const float* __restrict__ gamma,
        _Float16* __restrict__ attnO) {
    __shared__ __align__(16) char Sh[2][16384];   // K-only double buffer
    __shared__ float Ls[2][8][16];                // [map][wave][row16] l-partials

    int blk = blockIdx.x;
    // XCD-locality decode: bp group = (blk&7)*2 + ((blk>>3)&1); q-tile = blk>>4.
    int bp  = ((blk & 7) << 1) | ((blk >> 3) & 1);
    int r32 = blk >> 4;
    int p = bp & 7, bb = bp >> 3;
    int tid = threadIdx.x, lane = tid & 63, w = tid >> 6;
    int qt2 = w & 1, c = w >> 1;               // q-subtile, key-chunk of this wave
    int col16 = lane & 15, quad = lane >> 4;

    int qrow = bb * 2048 + r32 * 32 + qt2 * 16 + col16;
    const _Float16* qb = qbuf + (size_t)qrow * 512 + p * 64;
    half8 q1 = *(const half8*)(qb + quad * 8);
    half8 q2 = *(const half8*)(qb + 32 + quad * 8);

    // K staging: thread t handles chunks j0=(t>>8)*2 and j0+1, one 16B slot each.
    // LDS dest is linear per chunk: buf + j*4096 + (t&255)*16 (wave-uniform + lane*16).
    size_t bpoff = ((size_t)(bb * 8 + p)) << 18;              // 256KB per (b,p)
    int j0 = (tid >> 8) << 1;
    const char* ks = Kf + bpoff + ((size_t)j0 << 16) + ((tid & 255) << 4);
    int dko = (j0 << 12) + ((tid & 255) << 4);

    // V direct-from-global: per-wave chunk c, key-block kb = c*16 + it.
    const char* vsrc = Vf + bpoff + ((size_t)c << 16) + (lane << 4);

    const f32x4 minit = {-MSHIFT, -MSHIFT, -MSHIFT, -MSHIFT};

    float l1 = 0.f, l2 = 0.f;
    f32x4 o1[4] = {}, o2[4] = {};

    // prologue: stage K iter 0 into buffer 0
    gld16(ks, (char*)Sh + dko);
    gld16(ks + 65536, (char*)Sh + dko + 4096);

    for (int it = 0; it < 16; ++it) {          // 16 x 32 keys per chunk
        __syncthreads();                       // drains vmcnt -> K[it] valid; prev reads done

        // V fragments for THIS iteration: global -> VGPR (issued first; consumed by PV)
        half8 vf0 = *(const half8*)(vsrc);
        half8 vf1 = *(const half8*)(vsrc + 1024);
        half8 vf2 = *(const half8*)(vsrc + 2048);
        half8 vf3 = *(const half8*)(vsrc + 3072);
        vsrc += 4096;

        if (it + 1 < 16) {                     // prefetch K[it+1] into other buffer
            char* d = (char*)Sh + (((it + 1) & 1) << 14) + dko;
            gld16(ks + ((size_t)(it + 1) << 12), d);
            gld16(ks + 65536 + ((size_t)(it + 1) << 12), d + 4096);
        }
        const char* kvb = (char*)Sh + ((it & 1) << 14) + (c << 12) + (lane << 4);

        half8 kf0 = *(const half8*)(kvb);
        half8 kf1 = *(const half8*)(kvb + 1024);
        half8 kf2 = *(const half8*)(kvb + 2048);
        half8 kf3 = *(const half8*)(kvb + 3072);
        f32x4 sa1 = MFMA16(kf0, q1, minit), sb1 = MFMA16(kf1, q1, minit);
        f32x4 sa2 = MFMA16(kf2, q2, minit), sb2 = MFMA16(kf3, q2, minit);

        union { half8 v; fp16x2 h[4]; } p1u, p2u;
        {
            float a0 = EXP2(sa1[0]), a1 = EXP2(sa1[1]);
            float a2 = EXP2(sa1[2]), a3 = EXP2(sa1[3]);
            float b0 = EXP2(sb1[0]), b1 = EXP2(sb1[1]);
            float b2 = EXP2(sb1[2]), b3 = EXP2(sb1[3]);
            l1 += ((a0 + a1) + (a2 + a3)) + ((b0 + b1) + (b2 + b3));
            p1u.h[0] = __builtin_amdgcn_cvt_pkrtz(a0, a1);
            p1u.h[1] = __builtin_amdgcn_cvt_pkrtz(a2, a3);
            p1u.h[2] = __builtin_amdgcn_cvt_pkrtz(b0, b1);
            p1u.h[3] = __builtin_amdgcn_cvt_pkrtz(b2, b3);
        }
        {
            float a0 = EXP2(sa2[0]), a1 = EXP2(sa2[1]);
            float a2 = EXP2(sa2[2]), a3 = EXP2(sa2[3]);
            float b0 = EXP2(sb2[0]), b1 = EXP2(sb2[1]);
            float b2 = EXP2(sb2[2]), b3 = EXP2(sb2[3]);
            l2 += ((a0 + a1) + (a2 + a3)) + ((b0 + b1) + (b2 + b3));
            p2u.h[0] = __builtin_amdgcn_cvt_pkrtz(a0, a1);
            p2u.h[1] = __builtin_amdgcn_cvt_pkrtz(a2, a3);
            p2u.h[2] = __builtin_amdgcn_cvt_pkrtz(b0, b1);
            p2u.h[3] = __builtin_amdgcn_cvt_pkrtz(b2, b3);
        }
        o1[0] = MFMA16(p1u.v, vf0, o1[0]); o2[0] = MFMA16(p2u.v, vf0, o2[0]);
        o1[1] = MFMA16(p1u.v, vf1, o1[1]); o2[1] = MFMA16(p2u.v, vf1, o2[1]);
        o1[2] = MFMA16(p1u.v, vf2, o1[2]); o2[2] = MFMA16(p2u.v, vf2, o2[2]);
        o1[3] = MFMA16(p1u.v, vf3, o1[3]); o2[3] = MFMA16(p2u.v, vf3, o2[3]);
    }

    l1 += __shfl_xor(l1, 16); l1 += __shfl_xor(l1, 32);
    l2 += __shfl_xor(l2, 16); l2 += __shfl_xor(l2, 32);

    // ---- per-wave partials -> LDS (overlays BOTH K buffers; must sync first) ----
    __syncthreads();                           // all iter-15 K reads complete
    {
        _Float16* ob = (_Float16*)((char*)Sh + ((c * 2 + qt2) << 12)) + col16;
#pragma unroll
        for (int r = 0; r < 4; ++r) {
            _Float16* od = ob + (quad * 4 + r) * 128;
#pragma unroll
            for (int t = 0; t < 4; ++t) {
                od[t * 16]      = (_Float16)o1[t][r];
                od[64 + t * 16] = (_Float16)o2[t][r];
            }
        }
        if (quad == 0) { Ls[0][w][col16] = l1; Ls[1][w][col16] = l2; }
    }
    __syncthreads();

    // ---- fused combine: 512 threads = 32 rows x 16 ch-groups of 4 ----
    int rr = tid >> 4, jj = tid & 15;
    int qrt = rr >> 4, r16 = rr & 15;
    float o1s[4] = {}, o2s[4] = {};
    float l1s = 0.f, l2s = 0.f;
#pragma unroll
    for (int cc = 0; cc < 4; ++cc) {
        const _Float16* ob = (const _Float16*)((char*)Sh + ((cc * 2 + qrt) << 12))
                           + r16 * 128 + jj * 4;
        half4 a  = *(const half4*)ob;
        half4 b2 = *(const half4*)(ob + 64);
#pragma unroll
        for (int e = 0; e < 4; ++e) { o1s[e] += (float)a[e]; o2s[e] += (float)b2[e]; }
        l1s += Ls[0][cc * 2 + qrt][r16];
        l2s += Ls[1][cc * 2 + qrt][r16];
    }
    float s1 = 0.f, s2 = 0.f;
#pragma unroll
    for (int i = 0; i < 32; ++i) { s1 += lq1[i] * lk1[i]; s2 += lq2[i] * lk2[i]; }
    float lam = __expf(s1) - __expf(s2) + LAMBDA_INIT;
    float il1 = 1.f / l1s, il2 = lam / l2s;
    float Of[4], ss = 0.f;
#pragma unroll
    for (int e = 0; e < 4; ++e) { Of[e] = o1s[e] * il1 - o2s[e] * il2; ss += Of[e] * Of[e]; }
    ss += __shfl_xor(ss, 1, 16); ss += __shfl_xor(ss, 2, 16);
    ss += __shfl_xor(ss, 4, 16); ss += __shfl_xor(ss, 8, 16);
    float rms = sqrtf(ss * 0.015625f);
    float sc = OUT_SCALE / (rms + 1e-8f);
    half4 o;
#pragma unroll
    for (int e = 0; e < 4; ++e) o[e] = (_Float16)(gamma[jj * 4 + e] * Of[e] * sc);
    *(half4*)(attnO + ((size_t)(bb * 2048 + r32 * 32 + rr) * 512) + p * 64 + jj * 4) = o;
}

// ---------- GEMM2: attn @ Wout -> fp32 out ----------
__global__ __launch_bounds__(256) void k_gemm_out(const _Float16* __restrict__ attn,
                                                  const _Float16* __restrict__ WoutT,
                                                  float* __restrict__ out) {
    __shared__ __align__(16) char As[16384];
    __shared__ __align__(16) char Bs[16384];
    f32x4 acc[4][4] = {};
    int bm = blockIdx.x * 128, bn = blockIdx.y * 128;
    gemm_loop(attn, WoutT, 512, bm, bn, As, Bs, acc);

    int tid = threadIdx.x, lane = tid & 63, w = tid >> 6;
    int col16 = lane & 15, quad = lane >> 4;
    int wm = (w >> 1) << 6, wn = (w & 1) << 6;
#pragma unroll
    for (int i = 0; i < 4; ++i)
#pragma unroll
        for (int j = 0; j < 4; ++j) {
            int n = bn + wn + j * 16 + col16;
            int m0 = bm + wm + i * 16 + quad * 4;
#pragma unroll
            for (int r = 0; r < 4; ++r)
                out[(size_t)(m0 + r) * 1024 + n] = acc[i][j][r];
        }
}

// ---------- launch ----------
extern "C" void kernel_launch(void* const* d_in, const int* in_sizes, int n_in,
                              void* d_out, int out_size, void* d_ws, size_t ws_size,
                              hipStream_t stream) {
    const float* x     = (const float*)d_in[0];
    const float* Wq    = (const float*)d_in[1];
    const float* Wkv   = (const float*)d_in[2];
    const float* Wout  = (const float*)d_in[3];
    const float* lq1   = (const float*)d_in[4];
    const float* lk1   = (const float*)d_in[5];
    const float* lq2   = (const float*)d_in[6];
    const float* lk2   = (const float*)d_in[7];
    const float* gamma = (const float*)d_in[8];
    float* out = (float*)d_out;

    char* ws = (char*)d_ws;
    // Fused attention needs no Po/Pl partial buffers: peak ws = 29.36 MB.
    _Float16* xh    = (_Float16*)(ws);                 // 4096*1024  (8 MB, dead after qkv)
    _Float16* WallT = (_Float16*)(ws + 8388608);       // 1536*1024  (3 MB, dead after qkv)
    _Float16* WoutT = (_Float16*)(ws + 11534336);      // 1024*512   (1 MB)
    _Float16* qbuf  = (_Float16*)(ws + 12582912);      // 4096*512   (4 MB)
    char*     Kf    = (char*)(ws + 16777216);          // 16*64*4096 (4 MB)
    char*     Vf    = (char*)(ws + 20971520);          // 16*64*4096 (4 MB)
    _Float16* attn  = (_Float16*)(ws + 25165824);      // 4096*512   (4 MB) -> peak 29.36 MB

    k_prep<<<4608, 256, 0, stream>>>(x, Wq, Wkv, Wout, xh, WallT, WoutT);
    k_gemm_qkv<<<dim3(32, 12), 256, 0, stream>>>(xh, WallT, qbuf, Kf, Vf);
    k_attn_fused<<<1024, 512, 0, stream>>>(qbuf, Kf, Vf, lq1, lk1, lq2, lk2, gamma, attn);
    k_gemm_out<<<dim3(32, 8), 256, 0, stream>>>(attn, WoutT, out);
}